// Round 3
// baseline (7499.512 us; speedup 1.0000x reference)
//
#include <hip/hip_runtime.h>
#include <hip/hip_bf16.h>

#define N_MOLS      64
#define N_CONFS_PER 10
#define A_ATOMS     40
#define N_CONFS     640
#define N_ATOMS     25600
#define N_EDGES     409600
#define D           256
#define NG          32
#define NLAYERS     4
#define MOLB        512
#define H_MOL       384
#define EDGE_CAP    1024
#define SBP         260   // padded row stride (dwords) for lane-varying-row access
#define SHP         36    // padded sH row stride
#define EB          64    // edge batch

__device__ __forceinline__ float sspf(float x) {
    return fmaxf(x, 0.f) + log1pf(expf(-fabsf(x))) - 0.69314718055994531f;
}

// ---------------- edge bucketing by conformer ----------------
__global__ __launch_bounds__(256) void k_scatter(const int* __restrict__ nbr,
                                                 unsigned* __restrict__ cursors,
                                                 unsigned* __restrict__ esort) {
    int e = blockIdx.x * 256 + threadIdx.x;
    if (e >= N_EDGES) return;
    int a0 = nbr[2 * e], a1 = nbr[2 * e + 1];
    int conf = a0 / A_ATOMS;
    int a0l = a0 - conf * A_ATOMS;
    int a1l = a1 - conf * A_ATOMS;
    unsigned r = atomicAdd(&cursors[conf], 1u);
    if (r < EDGE_CAP) esort[conf * EDGE_CAP + r] = (unsigned)((a0l << 6) | a1l);
}

// dense helper: wave handles atoms [aw, aw+5), lane handles cols [c4, c4+4)
// acc[a][0..3] = bias[c4..c4+3] + sum_k src[aw+a][k] * W[k*D + c4..+3]
__device__ __forceinline__ void mmp(const float* __restrict__ src, int stride,
                                    const float* __restrict__ W,
                                    const float* __restrict__ bias,
                                    int aw, int c4, float4* acc) {
    const float4 b = *(const float4*)&bias[c4];
#pragma unroll
    for (int a = 0; a < 5; ++a) acc[a] = b;
#pragma unroll 4
    for (int k = 0; k < D; k += 4) {
        const float4 w0 = *(const float4*)&W[(k + 0) * D + c4];
        const float4 w1 = *(const float4*)&W[(k + 1) * D + c4];
        const float4 w2 = *(const float4*)&W[(k + 2) * D + c4];
        const float4 w3 = *(const float4*)&W[(k + 3) * D + c4];
#pragma unroll
        for (int a = 0; a < 5; ++a) {
            const float4 v = *(const float4*)&src[(aw + a) * stride + k];
            acc[a].x = fmaf(v.x, w0.x, fmaf(v.y, w1.x, fmaf(v.z, w2.x, fmaf(v.w, w3.x, acc[a].x))));
            acc[a].y = fmaf(v.x, w0.y, fmaf(v.y, w1.y, fmaf(v.z, w2.y, fmaf(v.w, w3.y, acc[a].y))));
            acc[a].z = fmaf(v.x, w0.z, fmaf(v.y, w1.z, fmaf(v.z, w2.z, fmaf(v.w, w3.z, acc[a].z))));
            acc[a].w = fmaf(v.x, w0.w, fmaf(v.y, w1.w, fmaf(v.z, w2.w, fmaf(v.w, w3.w, acc[a].w))));
        }
    }
}

// ---------------- main per-conformer kernel: 4 layers fully in LDS ----------------
__global__ __launch_bounds__(512, 2) void k_main(
    const int* __restrict__ z, const float* __restrict__ xyz,
    const float* __restrict__ emb,
    const float* __restrict__ We1, const float* __restrict__ be1,
    const float* __restrict__ We2, const float* __restrict__ be2,
    const float* __restrict__ Wn,  const float* __restrict__ bn,
    const float* __restrict__ Wu1, const float* __restrict__ bu1,
    const float* __restrict__ Wu2, const float* __restrict__ bu2,
    const unsigned* __restrict__ cursors, const unsigned* __restrict__ esort,
    float* __restrict__ conf_fp)
{
    __shared__ float sR[A_ATOMS * D];    // residual r        (broadcast reads only)
    __shared__ float sB[A_ATOMS * SBP];  // rn / t            (pad-260: lane-varying rows)
    __shared__ float sA[A_ATOMS * SBP];  // agg               (pad-260)
    __shared__ float sXYZ[A_ATOMS][3];
    __shared__ float sEG[EB * NG];       // e_g batch
    __shared__ float sH[EB * SHP];       // h batch (pad-36)
    __shared__ int   sE0[EB];
    __shared__ int   sE1[EB];
    __shared__ float sD[EB];
    __shared__ int   sZ[A_ATOMS];

    const int tid  = threadIdx.x;
    const int lane = tid & 63;
    const int wv   = tid >> 6;        // 0..7
    const int c4   = lane << 2;       // 0..252
    const int aw   = wv * 5;          // 5 atoms per wave
    const int conf = blockIdx.x;

    if (tid < A_ATOMS) {
        int ga = conf * A_ATOMS + tid;
        sZ[tid] = z[ga];
        sXYZ[tid][0] = xyz[ga * 3 + 0];
        sXYZ[tid][1] = xyz[ga * 3 + 1];
        sXYZ[tid][2] = xyz[ga * 3 + 2];
    }
    __syncthreads();
    {   // embedding init: (col, atom-half) split
        const int c = tid & 255, hh = tid >> 8;
#pragma unroll
        for (int a = 0; a < 20; ++a) {
            int aa = hh * 20 + a;
            sR[aa * D + c] = emb[sZ[aa] * D + c];
        }
    }
    int cnt = (int)cursors[conf];
    if (cnt > EDGE_CAP) cnt = EDGE_CAP;
    const unsigned* eptr = esort + conf * EDGE_CAP;

    for (int l = 0; l < NLAYERS; ++l) {
        __syncthreads();
        // ---- Phase A: sB = r @ Wn + bn; zero agg
        {
            float4 acc[5];
            mmp(sR, D, Wn + (size_t)l * D * D, bn + l * D, aw, c4, acc);
            const float4 z4 = make_float4(0.f, 0.f, 0.f, 0.f);
#pragma unroll
            for (int a = 0; a < 5; ++a) {
                *(float4*)&sB[(aw + a) * SBP + c4] = acc[a];
                *(float4*)&sA[(aw + a) * SBP + c4] = z4;
            }
        }
        __syncthreads();
        // ---- Phase B: edge batches of 64
        {
            const int t = tid & 31;
            float we1col[NG];
#pragma unroll
            for (int m = 0; m < NG; ++m) we1col[m] = We1[((size_t)l * NG + m) * NG + t];
            const float be1t = be1[l * NG + t];
            const int ccw = __builtin_amdgcn_readfirstlane(wv) * 32;  // wave's col chunk
            const float* __restrict__ We2w = We2 + (size_t)l * NG * D + ccw;
            const float* __restrict__ be2w = be2 + l * D + ccw;

            for (int base = 0; base < cnt; base += EB) {
                const int nb = min(EB, cnt - base);
                if (tid < nb) {
                    unsigned pe = eptr[base + tid];
                    int a0l = (pe >> 6) & 63, a1l = pe & 63;
                    sE0[tid] = a0l; sE1[tid] = a1l;
                    float dx = sXYZ[a0l][0] - sXYZ[a1l][0];
                    float dy = sXYZ[a0l][1] - sXYZ[a1l][1];
                    float dz = sXYZ[a0l][2] - sXYZ[a1l][2];
                    sD[tid] = sqrtf(dx * dx + dy * dy + dz * dz);
                }
                __syncthreads();
                {   // e_g: 64 edges x 32 gauss, 4/thread
                    int e = tid >> 3;
                    if (e < nb) {
                        float dd = sD[e] * (31.0f / 5.0f);
                        int m0 = (tid & 7) << 2;
                        float4 g;
                        float u0 = dd - (float)(m0 + 0);
                        float u1 = dd - (float)(m0 + 1);
                        float u2 = dd - (float)(m0 + 2);
                        float u3 = dd - (float)(m0 + 3);
                        g.x = expf(-0.5f * u0 * u0);
                        g.y = expf(-0.5f * u1 * u1);
                        g.z = expf(-0.5f * u2 * u2);
                        g.w = expf(-0.5f * u3 * u3);
                        *(float4*)&sEG[e * NG + m0] = g;
                    }
                }
                __syncthreads();
                {   // h = ssp(e_g @ We1 + be1): thread -> comp t, 4 edges
                    int e0 = tid >> 5;
#pragma unroll
                    for (int q = 0; q < 4; ++q) {
                        int e = e0 + (q << 4);
                        if (e < nb) {
                            float s = be1t;
#pragma unroll
                            for (int m = 0; m < NG; m += 4) {
                                const float4 g = *(const float4*)&sEG[e * NG + m];
                                s = fmaf(g.x, we1col[m], s);
                                s = fmaf(g.y, we1col[m + 1], s);
                                s = fmaf(g.z, we1col[m + 2], s);
                                s = fmaf(g.w, we1col[m + 3], s);
                            }
                            sH[e * SHP + t] = sspf(s);
                        }
                    }
                }
                __syncthreads();
                {   // ef + scatter: lane = edge, wave owns cols [ccw, ccw+32)
                    const int e = lane;
                    if (e < nb) {
                        float hreg[32];
#pragma unroll
                        for (int i = 0; i < 8; ++i) {
                            const float4 h4 = *(const float4*)&sH[e * SHP + 4 * i];
                            hreg[4 * i + 0] = h4.x; hreg[4 * i + 1] = h4.y;
                            hreg[4 * i + 2] = h4.z; hreg[4 * i + 3] = h4.w;
                        }
                        float ef[32];
#pragma unroll
                        for (int j = 0; j < 32; ++j) ef[j] = be2w[j];
#pragma unroll
                        for (int m = 0; m < NG; ++m) {
#pragma unroll
                            for (int j = 0; j < 32; ++j)
                                ef[j] = fmaf(hreg[m], We2w[m * D + j], ef[j]);
                        }
                        const int a0 = sE0[e], a1 = sE1[e];
                        const float* rn1 = &sB[a1 * SBP + ccw];
                        const float* rn0 = &sB[a0 * SBP + ccw];
                        float* g0 = &sA[a0 * SBP + ccw];
                        float* g1 = &sA[a1 * SBP + ccw];
#pragma unroll
                        for (int jq = 0; jq < 8; ++jq) {
                            const float4 v1 = *(const float4*)&rn1[4 * jq];
                            const float4 v0 = *(const float4*)&rn0[4 * jq];
                            atomicAdd(&g0[4 * jq + 0], v1.x * ef[4 * jq + 0]);
                            atomicAdd(&g0[4 * jq + 1], v1.y * ef[4 * jq + 1]);
                            atomicAdd(&g0[4 * jq + 2], v1.z * ef[4 * jq + 2]);
                            atomicAdd(&g0[4 * jq + 3], v1.w * ef[4 * jq + 3]);
                            atomicAdd(&g1[4 * jq + 0], v0.x * ef[4 * jq + 0]);
                            atomicAdd(&g1[4 * jq + 1], v0.y * ef[4 * jq + 1]);
                            atomicAdd(&g1[4 * jq + 2], v0.z * ef[4 * jq + 2]);
                            atomicAdd(&g1[4 * jq + 3], v0.w * ef[4 * jq + 3]);
                        }
                    }
                }
                __syncthreads();
            }
        }
        // ---- Phase C1: sB = ssp(agg @ Wu1 + bu1)
        {
            float4 acc[5];
            mmp(sA, SBP, Wu1 + (size_t)l * D * D, bu1 + l * D, aw, c4, acc);
#pragma unroll
            for (int a = 0; a < 5; ++a) {
                acc[a].x = sspf(acc[a].x); acc[a].y = sspf(acc[a].y);
                acc[a].z = sspf(acc[a].z); acc[a].w = sspf(acc[a].w);
                *(float4*)&sB[(aw + a) * SBP + c4] = acc[a];
            }
        }
        __syncthreads();
        // ---- Phase C2: r += t @ Wu2 + bu2
        {
            float4 acc[5];
            mmp(sB, SBP, Wu2 + (size_t)l * D * D, bu2 + l * D, aw, c4, acc);
#pragma unroll
            for (int a = 0; a < 5; ++a) {
                float4 cur = *(const float4*)&sR[(aw + a) * D + c4];
                cur.x += acc[a].x; cur.y += acc[a].y;
                cur.z += acc[a].z; cur.w += acc[a].w;
                *(float4*)&sR[(aw + a) * D + c4] = cur;
            }
        }
    }
    __syncthreads();
    if (tid < D) {
        float s = 0.f;
#pragma unroll
        for (int a = 0; a < A_ATOMS; ++a) s += sR[a * D + tid];
        conf_fp[conf * D + tid] = s;
    }
}

// ---------------- per-conformer molecular MLP + Boltzmann-weighted reduce ----------------
__global__ __launch_bounds__(512) void k_mol(
    const float* __restrict__ conf_fp,
    const float* __restrict__ Wm1, const float* __restrict__ bm1,
    const float* __restrict__ Wm2, const float* __restrict__ bm2,
    const float* __restrict__ boltz, float* __restrict__ mol_fp)
{
    __shared__ float cf[D];
    __shared__ float t[H_MOL];
    const int conf = blockIdx.x;
    const int tid = threadIdx.x;
    if (tid < D) cf[tid] = conf_fp[conf * D + tid];
    __syncthreads();
    if (tid < H_MOL) {
        float s = bm1[tid];
        for (int k = 0; k < D; k += 4) {
            const float4 v = *(const float4*)&cf[k];
            s = fmaf(v.x, Wm1[(k + 0) * H_MOL + tid], s);
            s = fmaf(v.y, Wm1[(k + 1) * H_MOL + tid], s);
            s = fmaf(v.z, Wm1[(k + 2) * H_MOL + tid], s);
            s = fmaf(v.w, Wm1[(k + 3) * H_MOL + tid], s);
        }
        t[tid] = sspf(s);
    }
    __syncthreads();
    {
        const int m = tid;  // 512 threads = MOLB
        float s = bm2[m];
        for (int h = 0; h < H_MOL; h += 4) {
            const float4 v = *(const float4*)&t[h];
            s = fmaf(v.x, Wm2[(h + 0) * MOLB + m], s);
            s = fmaf(v.y, Wm2[(h + 1) * MOLB + m], s);
            s = fmaf(v.z, Wm2[(h + 2) * MOLB + m], s);
            s = fmaf(v.w, Wm2[(h + 3) * MOLB + m], s);
        }
        atomicAdd(&mol_fp[(conf / N_CONFS_PER) * MOLB + m], s * boltz[conf]);
    }
}

// ---------------- final readout MLP + sigmoid ----------------
__global__ __launch_bounds__(256) void k_final(
    const float* __restrict__ mol_fp,
    const float* __restrict__ Wr1, const float* __restrict__ br1,
    const float* __restrict__ Wr2, const float* __restrict__ br2,
    float* __restrict__ out)
{
    __shared__ float mf[MOLB];
    __shared__ float t2[D];
    __shared__ float red[4];
    const int mol = blockIdx.x, tid = threadIdx.x;
    mf[tid]       = mol_fp[mol * MOLB + tid];
    mf[tid + 256] = mol_fp[mol * MOLB + tid + 256];
    __syncthreads();
    {
        float s = br1[tid];
        for (int k = 0; k < MOLB; k += 4) {
            const float4 v = *(const float4*)&mf[k];
            s = fmaf(v.x, Wr1[(k + 0) * D + tid], s);
            s = fmaf(v.y, Wr1[(k + 1) * D + tid], s);
            s = fmaf(v.z, Wr1[(k + 2) * D + tid], s);
            s = fmaf(v.w, Wr1[(k + 3) * D + tid], s);
        }
        t2[tid] = sspf(s);
    }
    __syncthreads();
    float p = t2[tid] * Wr2[tid];
#pragma unroll
    for (int o = 32; o > 0; o >>= 1) p += __shfl_down(p, o);
    if ((tid & 63) == 0) red[tid >> 6] = p;
    __syncthreads();
    if (tid == 0) {
        float logit = red[0] + red[1] + red[2] + red[3] + br2[0];
        out[mol] = 1.f / (1.f + expf(-logit));
    }
}

extern "C" void kernel_launch(void* const* d_in, const int* in_sizes, int n_in,
                              void* d_out, int out_size, void* d_ws, size_t ws_size,
                              hipStream_t stream)
{
    const int*   z     = (const int*)d_in[0];
    const float* xyz   = (const float*)d_in[1];
    const int*   nbr   = (const int*)d_in[2];
    const float* boltz = (const float*)d_in[3];
    const float* emb   = (const float*)d_in[4];
    const float* We1   = (const float*)d_in[5];
    const float* be1   = (const float*)d_in[6];
    const float* We2   = (const float*)d_in[7];
    const float* be2   = (const float*)d_in[8];
    const float* Wn    = (const float*)d_in[9];
    const float* bn    = (const float*)d_in[10];
    const float* Wu1   = (const float*)d_in[11];
    const float* bu1   = (const float*)d_in[12];
    const float* Wu2   = (const float*)d_in[13];
    const float* bu2   = (const float*)d_in[14];
    const float* Wm1   = (const float*)d_in[15];
    const float* bm1   = (const float*)d_in[16];
    const float* Wm2   = (const float*)d_in[17];
    const float* bm2   = (const float*)d_in[18];
    const float* Wr1   = (const float*)d_in[19];
    const float* br1   = (const float*)d_in[20];
    const float* Wr2   = (const float*)d_in[21];
    const float* br2   = (const float*)d_in[22];

    char* ws = (char*)d_ws;
    unsigned* cursors = (unsigned*)ws;                      // 640*4      = 2560 B
    float*    mol_fp  = (float*)(ws + 2560);                // 64*512*4   = 131072 B -> 133632
    unsigned* esort   = (unsigned*)(ws + 133632);           // 640*1024*4 = 2621440 B -> 2755072
    float*    conf_fp = (float*)(ws + 2755072);             // 640*256*4  = 655360 B

    hipMemsetAsync(cursors, 0, 2560 + 131072, stream);      // cursors + mol_fp
    k_scatter<<<(N_EDGES + 255) / 256, 256, 0, stream>>>(nbr, cursors, esort);
    k_main<<<N_CONFS, 512, 0, stream>>>(z, xyz, emb, We1, be1, We2, be2, Wn, bn,
                                        Wu1, bu1, Wu2, bu2, cursors, esort, conf_fp);
    k_mol<<<N_CONFS, 512, 0, stream>>>(conf_fp, Wm1, bm1, Wm2, bm2, boltz, mol_fp);
    k_final<<<N_MOLS, 256, 0, stream>>>(mol_fp, Wr1, br1, Wr2, br2, (float*)d_out);
}

// Round 4
// 2138.188 us; speedup vs baseline: 3.5074x; 3.5074x over previous
//
#include <hip/hip_runtime.h>
#include <hip/hip_bf16.h>

#define N_MOLS      64
#define N_CONFS_PER 10
#define A_ATOMS     40
#define N_CONFS     640
#define N_ATOMS     25600
#define N_EDGES     409600
#define D           256
#define NG          32
#define NLAYERS     4
#define MOLB        512
#define H_MOL       384
#define EDGE_CAP    1024
#define EB          32    // edge batch
#define SHP         36    // padded sHT row stride (16B-aligned rows)
#define LCAP        24    // per-atom incidence list capacity per batch

__device__ __forceinline__ float sspf(float x) {
    return fmaxf(x, 0.f) + log1pf(expf(-fabsf(x))) - 0.69314718055994531f;
}

// ---------------- edge bucketing by conformer ----------------
__global__ __launch_bounds__(256) void k_scatter(const int* __restrict__ nbr,
                                                 unsigned* __restrict__ cursors,
                                                 unsigned* __restrict__ esort) {
    int e = blockIdx.x * 256 + threadIdx.x;
    if (e >= N_EDGES) return;
    int a0 = nbr[2 * e], a1 = nbr[2 * e + 1];
    int conf = a0 / A_ATOMS;
    int a0l = a0 - conf * A_ATOMS;
    int a1l = a1 - conf * A_ATOMS;
    unsigned r = atomicAdd(&cursors[conf], 1u);
    if (r < EDGE_CAP) esort[conf * EDGE_CAP + r] = (unsigned)((a0l << 6) | a1l);
}

// dense helper: wave handles rows [aw, aw+5), lane handles cols [c4, c4+4)
__device__ __forceinline__ void mmp(const float* __restrict__ src,
                                    const float* __restrict__ W,
                                    const float* __restrict__ bias,
                                    int aw, int c4, float4* acc) {
    const float4 b = *(const float4*)&bias[c4];
#pragma unroll
    for (int a = 0; a < 5; ++a) acc[a] = b;
#pragma unroll 4
    for (int k = 0; k < D; k += 4) {
        const float4 w0 = *(const float4*)&W[(k + 0) * D + c4];
        const float4 w1 = *(const float4*)&W[(k + 1) * D + c4];
        const float4 w2 = *(const float4*)&W[(k + 2) * D + c4];
        const float4 w3 = *(const float4*)&W[(k + 3) * D + c4];
#pragma unroll
        for (int a = 0; a < 5; ++a) {
            const float4 v = *(const float4*)&src[(aw + a) * D + k];
            acc[a].x = fmaf(v.x, w0.x, fmaf(v.y, w1.x, fmaf(v.z, w2.x, fmaf(v.w, w3.x, acc[a].x))));
            acc[a].y = fmaf(v.x, w0.y, fmaf(v.y, w1.y, fmaf(v.z, w2.y, fmaf(v.w, w3.y, acc[a].y))));
            acc[a].z = fmaf(v.x, w0.z, fmaf(v.y, w1.z, fmaf(v.z, w2.z, fmaf(v.w, w3.z, acc[a].z))));
            acc[a].w = fmaf(v.x, w0.w, fmaf(v.y, w1.w, fmaf(v.z, w2.w, fmaf(v.w, w3.w, acc[a].w))));
        }
    }
}

// ---------------- main per-conformer kernel ----------------
__global__ __launch_bounds__(512, 2) void k_main(
    const int* __restrict__ z, const float* __restrict__ xyz,
    const float* __restrict__ emb,
    const float* __restrict__ We1, const float* __restrict__ be1,
    const float* __restrict__ We2, const float* __restrict__ be2,
    const float* __restrict__ Wn,  const float* __restrict__ bn,
    const float* __restrict__ Wu1, const float* __restrict__ bu1,
    const float* __restrict__ Wu2, const float* __restrict__ bu2,
    const unsigned* __restrict__ cursors, const unsigned* __restrict__ esort,
    float* __restrict__ conf_fp)
{
    __shared__ float sR[A_ATOMS * D];      // residual r (40KB)
    __shared__ float sB[A_ATOMS * D];      // rn -> agg -> t (40KB)
    __shared__ float sEF[EB * D];          // ef batch (32KB)
    __shared__ float sEG[EB * NG];         // e_g batch (4KB)
    __shared__ float sHT[NG * SHP];        // h transposed [comp][edge] (4.5KB)
    __shared__ int   sList[A_ATOMS * LCAP];// per-atom incidence (3.8KB)
    __shared__ int   sCnt[A_ATOMS];
    __shared__ float sXYZ[A_ATOMS][3];
    __shared__ int   sE0[EB], sE1[EB];
    __shared__ float sD[EB];
    __shared__ int   sZ[A_ATOMS];

    const int tid  = threadIdx.x;
    const int lane = tid & 63;
    const int wv   = tid >> 6;        // 0..7
    const int c4   = lane << 2;       // 0..252
    const int aw   = wv * 5;          // wave owns atoms [aw, aw+5)
    const int conf = blockIdx.x;

    if (tid < A_ATOMS) {
        int ga = conf * A_ATOMS + tid;
        sZ[tid] = z[ga];
        sXYZ[tid][0] = xyz[ga * 3 + 0];
        sXYZ[tid][1] = xyz[ga * 3 + 1];
        sXYZ[tid][2] = xyz[ga * 3 + 2];
    }
    __syncthreads();
    {   // embedding init
        const int c = tid & 255, hh = tid >> 8;
#pragma unroll
        for (int a = 0; a < 20; ++a) {
            int aa = hh * 20 + a;
            sR[aa * D + c] = emb[sZ[aa] * D + c];
        }
    }
    int cnt = (int)cursors[conf];
    if (cnt > EDGE_CAP) cnt = EDGE_CAP;
    const unsigned* eptr = esort + conf * EDGE_CAP;

    for (int l = 0; l < NLAYERS; ++l) {
        __syncthreads();
        // ---- Phase A: sB = r @ Wn + bn
        {
            float4 acc[5];
            mmp(sR, Wn + (size_t)l * D * D, bn + l * D, aw, c4, acc);
#pragma unroll
            for (int a = 0; a < 5; ++a) *(float4*)&sB[(aw + a) * D + c4] = acc[a];
        }
        __syncthreads();
        // ---- Phase B: edge batches of 32; agg in registers (gather form)
        float4 agg[5];
#pragma unroll
        for (int a = 0; a < 5; ++a) agg[a] = make_float4(0.f, 0.f, 0.f, 0.f);
        {
            const int t = tid & 31;
            float we1col[NG];
#pragma unroll
            for (int m = 0; m < NG; ++m) we1col[m] = We1[((size_t)l * NG + m) * NG + t];
            const float be1t = be1[l * NG + t];
            const float4 be2v = *(const float4*)&be2[l * D + c4];
            const float* __restrict__ We2l = We2 + (size_t)l * NG * D;

            for (int base = 0; base < cnt; base += EB) {
                const int nb = min(EB, cnt - base);
                // P1: unpack + distance; zero counters
                if (tid < nb) {
                    unsigned pe = eptr[base + tid];
                    int a0l = (pe >> 6) & 63, a1l = pe & 63;
                    sE0[tid] = a0l; sE1[tid] = a1l;
                    float dx = sXYZ[a0l][0] - sXYZ[a1l][0];
                    float dy = sXYZ[a0l][1] - sXYZ[a1l][1];
                    float dz = sXYZ[a0l][2] - sXYZ[a1l][2];
                    sD[tid] = sqrtf(dx * dx + dy * dy + dz * dz);
                }
                if (tid >= 64 && tid < 64 + A_ATOMS) sCnt[tid - 64] = 0;
                __syncthreads();
                // P2: e_g (2 gaussians/thread) + incidence list build (32 threads)
                {
                    int e = tid >> 4;
                    if (e < nb) {
                        float dd = sD[e] * (31.0f / 5.0f);
                        int m0 = (tid & 15) << 1;
                        float u0 = dd - (float)(m0 + 0);
                        float u1 = dd - (float)(m0 + 1);
                        float2 g;
                        g.x = expf(-0.5f * u0 * u0);
                        g.y = expf(-0.5f * u1 * u1);
                        *(float2*)&sEG[e * NG + m0] = g;
                    }
                }
                if (tid < nb) {
                    int a0 = sE0[tid], a1 = sE1[tid];
                    int i0 = atomicAdd(&sCnt[a0], 1);
                    if (i0 < LCAP) sList[a0 * LCAP + i0] = (a1 << 8) | tid;
                    int i1 = atomicAdd(&sCnt[a1], 1);
                    if (i1 < LCAP) sList[a1 * LCAP + i1] = (a0 << 8) | tid;
                }
                __syncthreads();
                // P3: hT[t][e] = ssp(e_g[e] . We1[:,t] + be1[t]), 2 edges/thread
                {
                    int e0 = tid >> 5;
#pragma unroll
                    for (int q = 0; q < 2; ++q) {
                        int e = e0 + (q << 4);
                        if (e < nb) {
                            float s = be1t;
#pragma unroll
                            for (int m = 0; m < NG; m += 4) {
                                const float4 g = *(const float4*)&sEG[e * NG + m];
                                s = fmaf(g.x, we1col[m], s);
                                s = fmaf(g.y, we1col[m + 1], s);
                                s = fmaf(g.z, we1col[m + 2], s);
                                s = fmaf(g.w, we1col[m + 3], s);
                            }
                            sHT[t * SHP + e] = sspf(s);
                        }
                    }
                }
                __syncthreads();
                // P4: ef = h @ We2 + be2 -> sEF. Wave wv does edges 4wv..4wv+3, lane cols c4.
                {
                    float4 ef0 = be2v, ef1 = be2v, ef2 = be2v, ef3 = be2v;
                    const int e0 = wv << 2;
#pragma unroll 8
                    for (int m = 0; m < NG; ++m) {
                        const float4 h4 = *(const float4*)&sHT[m * SHP + e0];
                        const float4 w4 = *(const float4*)&We2l[m * D + c4];
                        ef0.x = fmaf(h4.x, w4.x, ef0.x); ef0.y = fmaf(h4.x, w4.y, ef0.y);
                        ef0.z = fmaf(h4.x, w4.z, ef0.z); ef0.w = fmaf(h4.x, w4.w, ef0.w);
                        ef1.x = fmaf(h4.y, w4.x, ef1.x); ef1.y = fmaf(h4.y, w4.y, ef1.y);
                        ef1.z = fmaf(h4.y, w4.z, ef1.z); ef1.w = fmaf(h4.y, w4.w, ef1.w);
                        ef2.x = fmaf(h4.z, w4.x, ef2.x); ef2.y = fmaf(h4.z, w4.y, ef2.y);
                        ef2.z = fmaf(h4.z, w4.z, ef2.z); ef2.w = fmaf(h4.z, w4.w, ef2.w);
                        ef3.x = fmaf(h4.w, w4.x, ef3.x); ef3.y = fmaf(h4.w, w4.y, ef3.y);
                        ef3.z = fmaf(h4.w, w4.z, ef3.z); ef3.w = fmaf(h4.w, w4.w, ef3.w);
                    }
                    if (e0 + 0 < nb) *(float4*)&sEF[(e0 + 0) * D + c4] = ef0;
                    if (e0 + 1 < nb) *(float4*)&sEF[(e0 + 1) * D + c4] = ef1;
                    if (e0 + 2 < nb) *(float4*)&sEF[(e0 + 2) * D + c4] = ef2;
                    if (e0 + 3 < nb) *(float4*)&sEF[(e0 + 3) * D + c4] = ef3;
                }
                __syncthreads();
                // P5: gather into register agg — wave drains its own 5 atoms' lists
#pragma unroll
                for (int a = 0; a < 5; ++a) {
                    const int row = aw + a;
                    const int n = min(sCnt[row], LCAP);
                    for (int i = 0; i < n; ++i) {
                        const int ent = sList[row * LCAP + i];
                        const int e = ent & 255, o = ent >> 8;
                        const float4 f4 = *(const float4*)&sEF[e * D + c4];
                        const float4 r4 = *(const float4*)&sB[o * D + c4];
                        agg[a].x = fmaf(f4.x, r4.x, agg[a].x);
                        agg[a].y = fmaf(f4.y, r4.y, agg[a].y);
                        agg[a].z = fmaf(f4.z, r4.z, agg[a].z);
                        agg[a].w = fmaf(f4.w, r4.w, agg[a].w);
                    }
                }
                __syncthreads();
            }
        }
        // write agg into sB (rn dead now)
#pragma unroll
        for (int a = 0; a < 5; ++a) *(float4*)&sB[(aw + a) * D + c4] = agg[a];
        __syncthreads();
        // ---- Phase C1: sB = ssp(agg @ Wu1 + bu1)   (in-place per wave)
        {
            float4 acc[5];
            mmp(sB, Wu1 + (size_t)l * D * D, bu1 + l * D, aw, c4, acc);
#pragma unroll
            for (int a = 0; a < 5; ++a) {
                acc[a].x = sspf(acc[a].x); acc[a].y = sspf(acc[a].y);
                acc[a].z = sspf(acc[a].z); acc[a].w = sspf(acc[a].w);
                *(float4*)&sB[(aw + a) * D + c4] = acc[a];
            }
        }
        __syncthreads();
        // ---- Phase C2: r += t @ Wu2 + bu2
        {
            float4 acc[5];
            mmp(sB, Wu2 + (size_t)l * D * D, bu2 + l * D, aw, c4, acc);
#pragma unroll
            for (int a = 0; a < 5; ++a) {
                float4 cur = *(const float4*)&sR[(aw + a) * D + c4];
                cur.x += acc[a].x; cur.y += acc[a].y;
                cur.z += acc[a].z; cur.w += acc[a].w;
                *(float4*)&sR[(aw + a) * D + c4] = cur;
            }
        }
    }
    __syncthreads();
    if (tid < D) {
        float s = 0.f;
#pragma unroll
        for (int a = 0; a < A_ATOMS; ++a) s += sR[a * D + tid];
        conf_fp[conf * D + tid] = s;
    }
}

// ---------------- per-conformer molecular MLP + Boltzmann-weighted reduce ----------------
__global__ __launch_bounds__(512) void k_mol(
    const float* __restrict__ conf_fp,
    const float* __restrict__ Wm1, const float* __restrict__ bm1,
    const float* __restrict__ Wm2, const float* __restrict__ bm2,
    const float* __restrict__ boltz, float* __restrict__ mol_fp)
{
    __shared__ float cf[D];
    __shared__ float t[H_MOL];
    const int conf = blockIdx.x;
    const int tid = threadIdx.x;
    if (tid < D) cf[tid] = conf_fp[conf * D + tid];
    __syncthreads();
    if (tid < H_MOL) {
        float s = bm1[tid];
        for (int k = 0; k < D; k += 4) {
            const float4 v = *(const float4*)&cf[k];
            s = fmaf(v.x, Wm1[(k + 0) * H_MOL + tid], s);
            s = fmaf(v.y, Wm1[(k + 1) * H_MOL + tid], s);
            s = fmaf(v.z, Wm1[(k + 2) * H_MOL + tid], s);
            s = fmaf(v.w, Wm1[(k + 3) * H_MOL + tid], s);
        }
        t[tid] = sspf(s);
    }
    __syncthreads();
    {
        const int m = tid;
        float s = bm2[m];
        for (int h = 0; h < H_MOL; h += 4) {
            const float4 v = *(const float4*)&t[h];
            s = fmaf(v.x, Wm2[(h + 0) * MOLB + m], s);
            s = fmaf(v.y, Wm2[(h + 1) * MOLB + m], s);
            s = fmaf(v.z, Wm2[(h + 2) * MOLB + m], s);
            s = fmaf(v.w, Wm2[(h + 3) * MOLB + m], s);
        }
        atomicAdd(&mol_fp[(conf / N_CONFS_PER) * MOLB + m], s * boltz[conf]);
    }
}

// ---------------- final readout MLP + sigmoid ----------------
__global__ __launch_bounds__(256) void k_final(
    const float* __restrict__ mol_fp,
    const float* __restrict__ Wr1, const float* __restrict__ br1,
    const float* __restrict__ Wr2, const float* __restrict__ br2,
    float* __restrict__ out)
{
    __shared__ float mf[MOLB];
    __shared__ float t2[D];
    __shared__ float red[4];
    const int mol = blockIdx.x, tid = threadIdx.x;
    mf[tid]       = mol_fp[mol * MOLB + tid];
    mf[tid + 256] = mol_fp[mol * MOLB + tid + 256];
    __syncthreads();
    {
        float s = br1[tid];
        for (int k = 0; k < MOLB; k += 4) {
            const float4 v = *(const float4*)&mf[k];
            s = fmaf(v.x, Wr1[(k + 0) * D + tid], s);
            s = fmaf(v.y, Wr1[(k + 1) * D + tid], s);
            s = fmaf(v.z, Wr1[(k + 2) * D + tid], s);
            s = fmaf(v.w, Wr1[(k + 3) * D + tid], s);
        }
        t2[tid] = sspf(s);
    }
    __syncthreads();
    float p = t2[tid] * Wr2[tid];
#pragma unroll
    for (int o = 32; o > 0; o >>= 1) p += __shfl_down(p, o);
    if ((tid & 63) == 0) red[tid >> 6] = p;
    __syncthreads();
    if (tid == 0) {
        float logit = red[0] + red[1] + red[2] + red[3] + br2[0];
        out[mol] = 1.f / (1.f + expf(-logit));
    }
}

extern "C" void kernel_launch(void* const* d_in, const int* in_sizes, int n_in,
                              void* d_out, int out_size, void* d_ws, size_t ws_size,
                              hipStream_t stream)
{
    const int*   z     = (const int*)d_in[0];
    const float* xyz   = (const float*)d_in[1];
    const int*   nbr   = (const int*)d_in[2];
    const float* boltz = (const float*)d_in[3];
    const float* emb   = (const float*)d_in[4];
    const float* We1   = (const float*)d_in[5];
    const float* be1   = (const float*)d_in[6];
    const float* We2   = (const float*)d_in[7];
    const float* be2   = (const float*)d_in[8];
    const float* Wn    = (const float*)d_in[9];
    const float* bn    = (const float*)d_in[10];
    const float* Wu1   = (const float*)d_in[11];
    const float* bu1   = (const float*)d_in[12];
    const float* Wu2   = (const float*)d_in[13];
    const float* bu2   = (const float*)d_in[14];
    const float* Wm1   = (const float*)d_in[15];
    const float* bm1   = (const float*)d_in[16];
    const float* Wm2   = (const float*)d_in[17];
    const float* bm2   = (const float*)d_in[18];
    const float* Wr1   = (const float*)d_in[19];
    const float* br1   = (const float*)d_in[20];
    const float* Wr2   = (const float*)d_in[21];
    const float* br2   = (const float*)d_in[22];

    char* ws = (char*)d_ws;
    unsigned* cursors = (unsigned*)ws;                      // 640*4      = 2560 B
    float*    mol_fp  = (float*)(ws + 2560);                // 64*512*4   = 131072 B -> 133632
    unsigned* esort   = (unsigned*)(ws + 133632);           // 640*1024*4 = 2621440 B -> 2755072
    float*    conf_fp = (float*)(ws + 2755072);             // 640*256*4  = 655360 B

    hipMemsetAsync(cursors, 0, 2560 + 131072, stream);      // cursors + mol_fp
    k_scatter<<<(N_EDGES + 255) / 256, 256, 0, stream>>>(nbr, cursors, esort);
    k_main<<<N_CONFS, 512, 0, stream>>>(z, xyz, emb, We1, be1, We2, be2, Wn, bn,
                                        Wu1, bu1, Wu2, bu2, cursors, esort, conf_fp);
    k_mol<<<N_CONFS, 512, 0, stream>>>(conf_fp, Wm1, bm1, Wm2, bm2, boltz, mol_fp);
    k_final<<<N_MOLS, 256, 0, stream>>>(mol_fp, Wr1, br1, Wr2, br2, (float*)d_out);
}

// Round 5
// 1670.716 us; speedup vs baseline: 4.4888x; 1.2798x over previous
//
#include <hip/hip_runtime.h>
#include <hip/hip_bf16.h>

#define N_MOLS      64
#define N_CONFS_PER 10
#define A_ATOMS     40
#define N_CONFS     640
#define N_ATOMS     25600
#define N_EDGES     409600
#define D           256
#define NG          32
#define NLAYERS     4
#define MOLB        512
#define H_MOL       384
#define EDGE_CAP    1024
#define EB          32    // edge batch
#define SHP         36    // padded sHT row stride
#define LCAP        24    // per-atom incidence capacity per batch
#define SRP         260   // padded fp32 LDS row stride (2-way max on frag reads)

typedef __attribute__((ext_vector_type(8))) short bshort8;
typedef __attribute__((ext_vector_type(4))) float f32x4;

__device__ __forceinline__ float sspf(float x) {
    return fmaxf(x, 0.f) + log1pf(expf(-fabsf(x))) - 0.69314718055994531f;
}

// pack 8 consecutive fp32 -> bf16x8 fragment
__device__ __forceinline__ bshort8 cvt8(const float* __restrict__ p) {
    const float4 lo = *(const float4*)p;
    const float4 hi = *(const float4*)(p + 4);
    union { bshort8 s; __hip_bfloat16 h[8]; } u;
    u.h[0] = __float2bfloat16(lo.x); u.h[1] = __float2bfloat16(lo.y);
    u.h[2] = __float2bfloat16(lo.z); u.h[3] = __float2bfloat16(lo.w);
    u.h[4] = __float2bfloat16(hi.x); u.h[5] = __float2bfloat16(hi.y);
    u.h[6] = __float2bfloat16(hi.z); u.h[7] = __float2bfloat16(hi.w);
    return u.s;
}

// ---------------- weight prep: W[l][k][n] fp32 -> WT[mat][l][n][k] bf16 ----------------
__global__ __launch_bounds__(256) void k_prep(const float* __restrict__ Wn,
                                              const float* __restrict__ Wu1,
                                              const float* __restrict__ Wu2,
                                              __hip_bfloat16* __restrict__ WT) {
    int idx = blockIdx.x * 256 + threadIdx.x;       // 3*4*256*256
    int k = idx & 255;
    int n = (idx >> 8) & 255;
    int l = (idx >> 16) & 3;
    int mat = idx >> 18;
    const float* src = (mat == 0) ? Wn : (mat == 1) ? Wu1 : Wu2;
    WT[idx] = __float2bfloat16(src[((size_t)l * 256 + k) * 256 + n]);
}

// ---------------- edge bucketing by conformer ----------------
__global__ __launch_bounds__(256) void k_scatter(const int* __restrict__ nbr,
                                                 unsigned* __restrict__ cursors,
                                                 unsigned* __restrict__ esort) {
    int e = blockIdx.x * 256 + threadIdx.x;
    if (e >= N_EDGES) return;
    int a0 = nbr[2 * e], a1 = nbr[2 * e + 1];
    int conf = a0 / A_ATOMS;
    int a0l = a0 - conf * A_ATOMS;
    int a1l = a1 - conf * A_ATOMS;
    unsigned r = atomicAdd(&cursors[conf], 1u);
    if (r < EDGE_CAP) esort[conf * EDGE_CAP + r] = (unsigned)((a0l << 6) | a1l);
}

// dense MFMA: C(48x256) = src(48x256 fp32 LDS, pads zero) @ WT(bf16 [256n][256k])
// wave wv owns n-tiles {2wv, 2wv+1}; 3 m-tiles; K = 8 tiles of 32.
__device__ __forceinline__ void mfma_dense(const float* __restrict__ src,
                                           const __hip_bfloat16* __restrict__ WT,
                                           f32x4 acc[3][2], int lane, int wv) {
    const int r = lane & 15, g = lane >> 4;
#pragma unroll
    for (int mt = 0; mt < 3; ++mt)
#pragma unroll
        for (int j = 0; j < 2; ++j) acc[mt][j] = (f32x4){0.f, 0.f, 0.f, 0.f};
#pragma unroll 2
    for (int kt = 0; kt < 8; ++kt) {
        const int ko = kt * 32 + g * 8;
        bshort8 a0 = cvt8(&src[(0 * 16 + r) * SRP + ko]);
        bshort8 a1 = cvt8(&src[(1 * 16 + r) * SRP + ko]);
        bshort8 a2 = cvt8(&src[(2 * 16 + r) * SRP + ko]);
#pragma unroll
        for (int j = 0; j < 2; ++j) {
            const int nt = wv * 2 + j;
            bshort8 b = *(const bshort8*)&WT[(nt * 16 + r) * 256 + ko];
            acc[0][j] = __builtin_amdgcn_mfma_f32_16x16x32_bf16(a0, b, acc[0][j], 0, 0, 0);
            acc[1][j] = __builtin_amdgcn_mfma_f32_16x16x32_bf16(a1, b, acc[1][j], 0, 0, 0);
            acc[2][j] = __builtin_amdgcn_mfma_f32_16x16x32_bf16(a2, b, acc[2][j], 0, 0, 0);
        }
    }
}

// writeback: MODE 0: dst = acc+bias ; 1: dst = ssp(acc+bias) ; 2: dst += acc+bias
template <int MODE>
__device__ __forceinline__ void mfma_wb(const f32x4 acc[3][2], float* __restrict__ dst,
                                        const float* __restrict__ bias, int lane, int wv) {
    const int cc = lane & 15, g = lane >> 4;
    const int cr = g * 4;
#pragma unroll
    for (int j = 0; j < 2; ++j) {
        const int col = (wv * 2 + j) * 16 + cc;
        const float bv = bias[col];
#pragma unroll
        for (int mt = 0; mt < 3; ++mt) {
            if (mt == 2 && g >= 2) continue;   // rows 40..47 are padding
#pragma unroll
            for (int reg = 0; reg < 4; ++reg) {
                const int row = mt * 16 + cr + reg;
                float v = acc[mt][j][reg] + bv;
                if (MODE == 1) v = sspf(v);
                if (MODE == 2) v += dst[row * SRP + col];
                dst[row * SRP + col] = v;
            }
        }
    }
}

// ---------------- main per-conformer kernel ----------------
__global__ __launch_bounds__(512, 2) void k_main(
    const int* __restrict__ z, const float* __restrict__ xyz,
    const float* __restrict__ emb,
    const float* __restrict__ We1, const float* __restrict__ be1,
    const float* __restrict__ We2, const float* __restrict__ be2,
    const float* __restrict__ bn,
    const float* __restrict__ bu1, const float* __restrict__ bu2,
    const __hip_bfloat16* __restrict__ WT,
    const unsigned* __restrict__ cursors, const unsigned* __restrict__ esort,
    float* __restrict__ conf_fp)
{
    __shared__ float sR[48 * SRP];         // residual r, rows 40-47 zero (49.9KB)
    __shared__ float sB[48 * SRP];         // rn -> agg -> t, rows 40-47 zero (49.9KB)
    __shared__ float sEF[EB * D];          // ef batch (32KB)
    __shared__ float sEG[EB * NG];         // e_g batch (4KB)
    __shared__ float sHT[NG * SHP];        // h transposed [comp][edge] (4.5KB)
    __shared__ int   sList[A_ATOMS * LCAP];
    __shared__ int   sCnt[A_ATOMS];
    __shared__ float sXYZ[A_ATOMS][3];
    __shared__ int   sE0[EB], sE1[EB];
    __shared__ float sDall[EDGE_CAP];      // scaled distances, all edges (4KB)
    __shared__ int   sZ[A_ATOMS];

    const int tid  = threadIdx.x;
    const int lane = tid & 63;
    const int wv   = tid >> 6;        // 0..7
    const int c4   = lane << 2;       // 0..252
    const int aw   = wv * 5;          // wave owns atoms [aw, aw+5)
    const int conf = blockIdx.x;

    if (tid < A_ATOMS) {
        int ga = conf * A_ATOMS + tid;
        sZ[tid] = z[ga];
        sXYZ[tid][0] = xyz[ga * 3 + 0];
        sXYZ[tid][1] = xyz[ga * 3 + 1];
        sXYZ[tid][2] = xyz[ga * 3 + 2];
    }
    // zero pad rows 40..47 of sR, sB (stay zero forever)
    for (int i = tid; i < 8 * SRP; i += 512) {
        sR[40 * SRP + i] = 0.f;
        sB[40 * SRP + i] = 0.f;
    }
    __syncthreads();
    {   // embedding init
        const int c = tid & 255, hh = tid >> 8;
#pragma unroll
        for (int a = 0; a < 20; ++a) {
            int aa = hh * 20 + a;
            sR[aa * SRP + c] = emb[sZ[aa] * D + c];
        }
    }
    int cnt = (int)cursors[conf];
    if (cnt > EDGE_CAP) cnt = EDGE_CAP;
    const unsigned* eptr = esort + conf * EDGE_CAP;
    // all-edge scaled distances (once per conf)
    for (int i = tid; i < cnt; i += 512) {
        unsigned pe = eptr[i];
        int a0l = (pe >> 6) & 63, a1l = pe & 63;
        float dx = sXYZ[a0l][0] - sXYZ[a1l][0];
        float dy = sXYZ[a0l][1] - sXYZ[a1l][1];
        float dz = sXYZ[a0l][2] - sXYZ[a1l][2];
        sDall[i] = sqrtf(dx * dx + dy * dy + dz * dz) * (31.0f / 5.0f);
    }

    for (int l = 0; l < NLAYERS; ++l) {
        __syncthreads();
        // ---- M1: sB = r @ Wn + bn   (MFMA)
        {
            f32x4 acc[3][2];
            mfma_dense(sR, WT + ((size_t)(0 * 4 + l) << 16), acc, lane, wv);
            mfma_wb<0>(acc, sB, bn + l * D, lane, wv);
        }
        __syncthreads();
        // ---- Phase B: edge batches of 32; agg in registers (gather form)
        float4 agg[5];
#pragma unroll
        for (int a = 0; a < 5; ++a) agg[a] = make_float4(0.f, 0.f, 0.f, 0.f);
        {
            const int t = tid & 31;
            float we1col[NG];
#pragma unroll
            for (int m = 0; m < NG; ++m) we1col[m] = We1[((size_t)l * NG + m) * NG + t];
            const float be1t = be1[l * NG + t];
            const float4 be2v = *(const float4*)&be2[l * D + c4];
            const float* __restrict__ We2l = We2 + (size_t)l * NG * D;

            for (int base = 0; base < cnt; base += EB) {
                const int nb = min(EB, cnt - base);
                // X1: unpack endpoints + zero counters + e_g
                if (tid < nb) {
                    unsigned pe = eptr[base + tid];
                    sE0[tid] = (pe >> 6) & 63;
                    sE1[tid] = pe & 63;
                }
                if (tid >= 64 && tid < 64 + A_ATOMS) sCnt[tid - 64] = 0;
                {
                    int e = tid >> 4;
                    if (e < nb) {
                        float dd = sDall[base + e];
                        int m0 = (tid & 15) << 1;
                        float u0 = dd - (float)(m0 + 0);
                        float u1 = dd - (float)(m0 + 1);
                        float2 g;
                        g.x = expf(-0.5f * u0 * u0);
                        g.y = expf(-0.5f * u1 * u1);
                        *(float2*)&sEG[e * NG + m0] = g;
                    }
                }
                __syncthreads();
                // X2: incidence lists + h = ssp(e_g @ We1 + be1)
                if (tid < nb) {
                    int a0 = sE0[tid], a1 = sE1[tid];
                    int i0 = atomicAdd(&sCnt[a0], 1);
                    if (i0 < LCAP) sList[a0 * LCAP + i0] = (a1 << 8) | tid;
                    int i1 = atomicAdd(&sCnt[a1], 1);
                    if (i1 < LCAP) sList[a1 * LCAP + i1] = (a0 << 8) | tid;
                }
                {
                    int e0 = tid >> 5;
#pragma unroll
                    for (int q = 0; q < 2; ++q) {
                        int e = e0 + (q << 4);
                        if (e < nb) {
                            float s = be1t;
#pragma unroll
                            for (int m = 0; m < NG; m += 4) {
                                const float4 g = *(const float4*)&sEG[e * NG + m];
                                s = fmaf(g.x, we1col[m], s);
                                s = fmaf(g.y, we1col[m + 1], s);
                                s = fmaf(g.z, we1col[m + 2], s);
                                s = fmaf(g.w, we1col[m + 3], s);
                            }
                            sHT[t * SHP + e] = sspf(s);
                        }
                    }
                }
                __syncthreads();
                // P4: ef = h @ We2 + be2 -> sEF (wave wv: edges 4wv..4wv+3, lane cols c4)
                {
                    float4 ef0 = be2v, ef1 = be2v, ef2 = be2v, ef3 = be2v;
                    const int e0 = wv << 2;
#pragma unroll 8
                    for (int m = 0; m < NG; ++m) {
                        const float4 h4 = *(const float4*)&sHT[m * SHP + e0];
                        const float4 w4 = *(const float4*)&We2l[m * D + c4];
                        ef0.x = fmaf(h4.x, w4.x, ef0.x); ef0.y = fmaf(h4.x, w4.y, ef0.y);
                        ef0.z = fmaf(h4.x, w4.z, ef0.z); ef0.w = fmaf(h4.x, w4.w, ef0.w);
                        ef1.x = fmaf(h4.y, w4.x, ef1.x); ef1.y = fmaf(h4.y, w4.y, ef1.y);
                        ef1.z = fmaf(h4.y, w4.z, ef1.z); ef1.w = fmaf(h4.y, w4.w, ef1.w);
                        ef2.x = fmaf(h4.z, w4.x, ef2.x); ef2.y = fmaf(h4.z, w4.y, ef2.y);
                        ef2.z = fmaf(h4.z, w4.z, ef2.z); ef2.w = fmaf(h4.z, w4.w, ef2.w);
                        ef3.x = fmaf(h4.w, w4.x, ef3.x); ef3.y = fmaf(h4.w, w4.y, ef3.y);
                        ef3.z = fmaf(h4.w, w4.z, ef3.z); ef3.w = fmaf(h4.w, w4.w, ef3.w);
                    }
                    if (e0 + 0 < nb) *(float4*)&sEF[(e0 + 0) * D + c4] = ef0;
                    if (e0 + 1 < nb) *(float4*)&sEF[(e0 + 1) * D + c4] = ef1;
                    if (e0 + 2 < nb) *(float4*)&sEF[(e0 + 2) * D + c4] = ef2;
                    if (e0 + 3 < nb) *(float4*)&sEF[(e0 + 3) * D + c4] = ef3;
                }
                __syncthreads();
                // P5: gather into register agg (wave drains its own 5 atoms)
#pragma unroll
                for (int a = 0; a < 5; ++a) {
                    const int row = aw + a;
                    const int n = min(sCnt[row], LCAP);
                    for (int i = 0; i < n; ++i) {
                        const int ent = sList[row * LCAP + i];
                        const int e = ent & 255, o = ent >> 8;
                        const float4 f4 = *(const float4*)&sEF[e * D + c4];
                        const float4 r4 = *(const float4*)&sB[o * SRP + c4];
                        agg[a].x = fmaf(f4.x, r4.x, agg[a].x);
                        agg[a].y = fmaf(f4.y, r4.y, agg[a].y);
                        agg[a].z = fmaf(f4.z, r4.z, agg[a].z);
                        agg[a].w = fmaf(f4.w, r4.w, agg[a].w);
                    }
                }
                __syncthreads();
            }
        }
        // agg -> sB (rn dead)
#pragma unroll
        for (int a = 0; a < 5; ++a) *(float4*)&sB[(aw + a) * SRP + c4] = agg[a];
        __syncthreads();
        // ---- M2: sB = ssp(agg @ Wu1 + bu1)  (in-place: sync between acc and wb)
        {
            f32x4 acc[3][2];
            mfma_dense(sB, WT + ((size_t)(1 * 4 + l) << 16), acc, lane, wv);
            __syncthreads();
            mfma_wb<1>(acc, sB, bu1 + l * D, lane, wv);
        }
        __syncthreads();
        // ---- M3: sR += t @ Wu2 + bu2
        {
            f32x4 acc[3][2];
            mfma_dense(sB, WT + ((size_t)(2 * 4 + l) << 16), acc, lane, wv);
            mfma_wb<2>(acc, sR, bu2 + l * D, lane, wv);
        }
    }
    __syncthreads();
    if (tid < D) {
        float s = 0.f;
#pragma unroll
        for (int a = 0; a < A_ATOMS; ++a) s += sR[a * SRP + tid];
        conf_fp[conf * D + tid] = s;
    }
}

// ---------------- per-conformer molecular MLP + Boltzmann-weighted reduce ----------------
__global__ __launch_bounds__(512) void k_mol(
    const float* __restrict__ conf_fp,
    const float* __restrict__ Wm1, const float* __restrict__ bm1,
    const float* __restrict__ Wm2, const float* __restrict__ bm2,
    const float* __restrict__ boltz, float* __restrict__ mol_fp)
{
    __shared__ float cf[D];
    __shared__ float t[H_MOL];
    const int conf = blockIdx.x;
    const int tid = threadIdx.x;
    if (tid < D) cf[tid] = conf_fp[conf * D + tid];
    __syncthreads();
    if (tid < H_MOL) {
        float s = bm1[tid];
        for (int k = 0; k < D; k += 4) {
            const float4 v = *(const float4*)&cf[k];
            s = fmaf(v.x, Wm1[(k + 0) * H_MOL + tid], s);
            s = fmaf(v.y, Wm1[(k + 1) * H_MOL + tid], s);
            s = fmaf(v.z, Wm1[(k + 2) * H_MOL + tid], s);
            s = fmaf(v.w, Wm1[(k + 3) * H_MOL + tid], s);
        }
        t[tid] = sspf(s);
    }
    __syncthreads();
    {
        const int m = tid;
        float s = bm2[m];
        for (int h = 0; h < H_MOL; h += 4) {
            const float4 v = *(const float4*)&t[h];
            s = fmaf(v.x, Wm2[(h + 0) * MOLB + m], s);
            s = fmaf(v.y, Wm2[(h + 1) * MOLB + m], s);
            s = fmaf(v.z, Wm2[(h + 2) * MOLB + m], s);
            s = fmaf(v.w, Wm2[(h + 3) * MOLB + m], s);
        }
        atomicAdd(&mol_fp[(conf / N_CONFS_PER) * MOLB + m], s * boltz[conf]);
    }
}

// ---------------- final readout MLP + sigmoid ----------------
__global__ __launch_bounds__(256) void k_final(
    const float* __restrict__ mol_fp,
    const float* __restrict__ Wr1, const float* __restrict__ br1,
    const float* __restrict__ Wr2, const float* __restrict__ br2,
    float* __restrict__ out)
{
    __shared__ float mf[MOLB];
    __shared__ float t2[D];
    __shared__ float red[4];
    const int mol = blockIdx.x, tid = threadIdx.x;
    mf[tid]       = mol_fp[mol * MOLB + tid];
    mf[tid + 256] = mol_fp[mol * MOLB + tid + 256];
    __syncthreads();
    {
        float s = br1[tid];
        for (int k = 0; k < MOLB; k += 4) {
            const float4 v = *(const float4*)&mf[k];
            s = fmaf(v.x, Wr1[(k + 0) * D + tid], s);
            s = fmaf(v.y, Wr1[(k + 1) * D + tid], s);
            s = fmaf(v.z, Wr1[(k + 2) * D + tid], s);
            s = fmaf(v.w, Wr1[(k + 3) * D + tid], s);
        }
        t2[tid] = sspf(s);
    }
    __syncthreads();
    float p = t2[tid] * Wr2[tid];
#pragma unroll
    for (int o = 32; o > 0; o >>= 1) p += __shfl_down(p, o);
    if ((tid & 63) == 0) red[tid >> 6] = p;
    __syncthreads();
    if (tid == 0) {
        float logit = red[0] + red[1] + red[2] + red[3] + br2[0];
        out[mol] = 1.f / (1.f + expf(-logit));
    }
}

extern "C" void kernel_launch(void* const* d_in, const int* in_sizes, int n_in,
                              void* d_out, int out_size, void* d_ws, size_t ws_size,
                              hipStream_t stream)
{
    const int*   z     = (const int*)d_in[0];
    const float* xyz   = (const float*)d_in[1];
    const int*   nbr   = (const int*)d_in[2];
    const float* boltz = (const float*)d_in[3];
    const float* emb   = (const float*)d_in[4];
    const float* We1   = (const float*)d_in[5];
    const float* be1   = (const float*)d_in[6];
    const float* We2   = (const float*)d_in[7];
    const float* be2   = (const float*)d_in[8];
    const float* Wn    = (const float*)d_in[9];
    const float* bn    = (const float*)d_in[10];
    const float* Wu1   = (const float*)d_in[11];
    const float* bu1   = (const float*)d_in[12];
    const float* Wu2   = (const float*)d_in[13];
    const float* bu2   = (const float*)d_in[14];
    const float* Wm1   = (const float*)d_in[15];
    const float* bm1   = (const float*)d_in[16];
    const float* Wm2   = (const float*)d_in[17];
    const float* bm2   = (const float*)d_in[18];
    const float* Wr1   = (const float*)d_in[19];
    const float* br1   = (const float*)d_in[20];
    const float* Wr2   = (const float*)d_in[21];
    const float* br2   = (const float*)d_in[22];

    char* ws = (char*)d_ws;
    unsigned* cursors        = (unsigned*)ws;                   // 2560 B
    float*    mol_fp         = (float*)(ws + 2560);             // 131072 B -> 133632
    unsigned* esort          = (unsigned*)(ws + 133632);        // 2621440 B -> 2755072
    float*    conf_fp        = (float*)(ws + 2755072);          // 655360 B -> 3410432
    __hip_bfloat16* WT       = (__hip_bfloat16*)(ws + 3410432); // 3*4*65536*2 = 1572864 B

    hipMemsetAsync(cursors, 0, 2560 + 131072, stream);          // cursors + mol_fp
    k_prep<<<3072, 256, 0, stream>>>(Wn, Wu1, Wu2, WT);
    k_scatter<<<(N_EDGES + 255) / 256, 256, 0, stream>>>(nbr, cursors, esort);
    k_main<<<N_CONFS, 512, 0, stream>>>(z, xyz, emb, We1, be1, We2, be2, bn,
                                        bu1, bu2, WT, cursors, esort, conf_fp);
    k_mol<<<N_CONFS, 512, 0, stream>>>(conf_fp, Wm1, bm1, Wm2, bm2, boltz, mol_fp);
    k_final<<<N_MOLS, 256, 0, stream>>>(mol_fp, Wr1, br1, Wr2, br2, (float*)d_out);
}

// Round 6
// 1193.177 us; speedup vs baseline: 6.2853x; 1.4002x over previous
//
#include <hip/hip_runtime.h>
#include <hip/hip_bf16.h>

#define N_MOLS      64
#define N_CONFS_PER 10
#define A_ATOMS     40
#define N_CONFS     640
#define N_ATOMS     25600
#define N_EDGES     409600
#define D           256
#define NG          32
#define NLAYERS     4
#define MOLB        512
#define H_MOL       384
#define EDGE_CAP    1024
#define EB          64    // edge batch
#define SHBP        36    // sHb row stride in halfwords (72B: odd*8 -> spreads banks)
#define LCAP        20    // per-atom incidence capacity per 64-edge batch (mean 3.2)
#define SRP         260   // padded fp32 LDS row stride

typedef __attribute__((ext_vector_type(8))) short bshort8;
typedef __attribute__((ext_vector_type(4))) float f32x4;

__device__ __forceinline__ float sspf(float x) {
    return fmaxf(x, 0.f) + log1pf(expf(-fabsf(x))) - 0.69314718055994531f;
}
__device__ __forceinline__ float b2f(short s) {
    union { unsigned u; float f; } u;
    u.u = ((unsigned)(unsigned short)s) << 16;
    return u.f;
}
__device__ __forceinline__ short f2b(float x) {
    __hip_bfloat16 h = __float2bfloat16(x);
    return *reinterpret_cast<short*>(&h);
}

// pack 8 consecutive fp32 -> bf16x8 fragment
__device__ __forceinline__ bshort8 cvt8(const float* __restrict__ p) {
    const float4 lo = *(const float4*)p;
    const float4 hi = *(const float4*)(p + 4);
    union { bshort8 s; __hip_bfloat16 h[8]; } u;
    u.h[0] = __float2bfloat16(lo.x); u.h[1] = __float2bfloat16(lo.y);
    u.h[2] = __float2bfloat16(lo.z); u.h[3] = __float2bfloat16(lo.w);
    u.h[4] = __float2bfloat16(hi.x); u.h[5] = __float2bfloat16(hi.y);
    u.h[6] = __float2bfloat16(hi.z); u.h[7] = __float2bfloat16(hi.w);
    return u.s;
}

// ---------------- weight prep: dense W[l][k][n] fp32 -> WT[mat][l][n][k] bf16 ----------------
__global__ __launch_bounds__(256) void k_prep(const float* __restrict__ Wn,
                                              const float* __restrict__ Wu1,
                                              const float* __restrict__ Wu2,
                                              __hip_bfloat16* __restrict__ WT) {
    int idx = blockIdx.x * 256 + threadIdx.x;       // 3*4*256*256
    int k = idx & 255;
    int n = (idx >> 8) & 255;
    int l = (idx >> 16) & 3;
    int mat = idx >> 18;
    const float* src = (mat == 0) ? Wn : (mat == 1) ? Wu1 : Wu2;
    WT[idx] = __float2bfloat16(src[((size_t)l * 256 + k) * 256 + n]);
}

// We2[l][k(32)][n(256)] fp32 -> WT2[l][n][k] bf16
__global__ __launch_bounds__(256) void k_prep2(const float* __restrict__ We2,
                                               __hip_bfloat16* __restrict__ WT2) {
    int idx = blockIdx.x * 256 + threadIdx.x;       // 4*256*32
    int k = idx & 31;
    int n = (idx >> 5) & 255;
    int l = idx >> 13;
    WT2[idx] = __float2bfloat16(We2[((size_t)l * 32 + k) * 256 + n]);
}

// ---------------- edge bucketing by conformer ----------------
__global__ __launch_bounds__(256) void k_scatter(const int* __restrict__ nbr,
                                                 unsigned* __restrict__ cursors,
                                                 unsigned* __restrict__ esort) {
    int e = blockIdx.x * 256 + threadIdx.x;
    if (e >= N_EDGES) return;
    int a0 = nbr[2 * e], a1 = nbr[2 * e + 1];
    int conf = a0 / A_ATOMS;
    int a0l = a0 - conf * A_ATOMS;
    int a1l = a1 - conf * A_ATOMS;
    unsigned r = atomicAdd(&cursors[conf], 1u);
    if (r < EDGE_CAP) esort[conf * EDGE_CAP + r] = (unsigned)((a0l << 6) | a1l);
}

// dense MFMA: C(48x256) = src(48x256 fp32 LDS, pads zero) @ WT(bf16 [256n][256k])
__device__ __forceinline__ void mfma_dense(const float* __restrict__ src,
                                           const __hip_bfloat16* __restrict__ WT,
                                           f32x4 acc[3][2], int lane, int wv) {
    const int r = lane & 15, g = lane >> 4;
#pragma unroll
    for (int mt = 0; mt < 3; ++mt)
#pragma unroll
        for (int j = 0; j < 2; ++j) acc[mt][j] = (f32x4){0.f, 0.f, 0.f, 0.f};
#pragma unroll 2
    for (int kt = 0; kt < 8; ++kt) {
        const int ko = kt * 32 + g * 8;
        bshort8 a0 = cvt8(&src[(0 * 16 + r) * SRP + ko]);
        bshort8 a1 = cvt8(&src[(1 * 16 + r) * SRP + ko]);
        bshort8 a2 = cvt8(&src[(2 * 16 + r) * SRP + ko]);
#pragma unroll
        for (int j = 0; j < 2; ++j) {
            const int nt = wv * 2 + j;
            bshort8 b = *(const bshort8*)&WT[(nt * 16 + r) * 256 + ko];
            acc[0][j] = __builtin_amdgcn_mfma_f32_16x16x32_bf16(a0, b, acc[0][j], 0, 0, 0);
            acc[1][j] = __builtin_amdgcn_mfma_f32_16x16x32_bf16(a1, b, acc[1][j], 0, 0, 0);
            acc[2][j] = __builtin_amdgcn_mfma_f32_16x16x32_bf16(a2, b, acc[2][j], 0, 0, 0);
        }
    }
}

// writeback: MODE 0: dst = acc+bias ; 1: dst = ssp(acc+bias) ; 2: dst += acc+bias
template <int MODE>
__device__ __forceinline__ void mfma_wb(const f32x4 acc[3][2], float* __restrict__ dst,
                                        const float* __restrict__ bias, int lane, int wv) {
    const int cc = lane & 15, g = lane >> 4;
    const int cr = g * 4;
#pragma unroll
    for (int j = 0; j < 2; ++j) {
        const int col = (wv * 2 + j) * 16 + cc;
        const float bv = bias[col];
#pragma unroll
        for (int mt = 0; mt < 3; ++mt) {
            if (mt == 2 && g >= 2) continue;   // rows 40..47 are padding
#pragma unroll
            for (int reg = 0; reg < 4; ++reg) {
                const int row = mt * 16 + cr + reg;
                float v = acc[mt][j][reg] + bv;
                if (MODE == 1) v = sspf(v);
                if (MODE == 2) v += dst[row * SRP + col];
                dst[row * SRP + col] = v;
            }
        }
    }
}

// ---------------- main per-conformer kernel ----------------
__global__ __launch_bounds__(512, 2) void k_main(
    const int* __restrict__ z, const float* __restrict__ xyz,
    const float* __restrict__ emb,
    const float* __restrict__ We1, const float* __restrict__ be1,
    const float* __restrict__ be2,
    const float* __restrict__ bn,
    const float* __restrict__ bu1, const float* __restrict__ bu2,
    const __hip_bfloat16* __restrict__ WT,
    const __hip_bfloat16* __restrict__ WT2,
    const unsigned* __restrict__ cursors, const unsigned* __restrict__ esort,
    float* __restrict__ conf_fp)
{
    __shared__ float sR[48 * SRP];         // residual r, rows 40-47 zero (49.9KB)
    __shared__ float sB[48 * SRP];         // rn -> agg -> t (49.9KB)
    __shared__ short sEFs[EB * 256];       // ef batch, bf16 bits (32KB)
    __shared__ float sEG[EB * NG];         // e_g batch (8KB)
    __shared__ short sHb[EB * SHBP];       // h batch, bf16 [edge][k] pad-36 (4.5KB)
    __shared__ int   sList[A_ATOMS * LCAP];
    __shared__ int   sCnt[A_ATOMS];
    __shared__ float sXYZ[A_ATOMS][3];
    __shared__ int   sE0[EB], sE1[EB];
    __shared__ float sDall[EDGE_CAP];      // scaled distances (4KB)
    __shared__ int   sZ[A_ATOMS];

    const int tid  = threadIdx.x;
    const int lane = tid & 63;
    const int wv   = tid >> 6;        // 0..7
    const int c4   = lane << 2;       // 0..252
    const int aw   = wv * 5;          // wave owns atoms [aw, aw+5)
    const int conf = blockIdx.x;

    if (tid < A_ATOMS) {
        int ga = conf * A_ATOMS + tid;
        sZ[tid] = z[ga];
        sXYZ[tid][0] = xyz[ga * 3 + 0];
        sXYZ[tid][1] = xyz[ga * 3 + 1];
        sXYZ[tid][2] = xyz[ga * 3 + 2];
    }
    for (int i = tid; i < 8 * SRP; i += 512) {   // zero pad rows 40..47
        sR[40 * SRP + i] = 0.f;
        sB[40 * SRP + i] = 0.f;
    }
    __syncthreads();
    {   // embedding init
        const int c = tid & 255, hh = tid >> 8;
#pragma unroll
        for (int a = 0; a < 20; ++a) {
            int aa = hh * 20 + a;
            sR[aa * SRP + c] = emb[sZ[aa] * D + c];
        }
    }
    int cnt = (int)cursors[conf];
    if (cnt > EDGE_CAP) cnt = EDGE_CAP;
    const unsigned* eptr = esort + conf * EDGE_CAP;
    for (int i = tid; i < cnt; i += 512) {
        unsigned pe = eptr[i];
        int a0l = (pe >> 6) & 63, a1l = pe & 63;
        float dx = sXYZ[a0l][0] - sXYZ[a1l][0];
        float dy = sXYZ[a0l][1] - sXYZ[a1l][1];
        float dz = sXYZ[a0l][2] - sXYZ[a1l][2];
        sDall[i] = sqrtf(dx * dx + dy * dy + dz * dz) * (31.0f / 5.0f);
    }

    for (int l = 0; l < NLAYERS; ++l) {
        __syncthreads();
        // ---- M1: sB = r @ Wn + bn   (MFMA)
        {
            f32x4 acc[3][2];
            mfma_dense(sR, WT + ((size_t)(0 * 4 + l) << 16), acc, lane, wv);
            mfma_wb<0>(acc, sB, bn + l * D, lane, wv);
        }
        __syncthreads();
        // ---- edge phase: batches of 64
        float4 agg[5];
#pragma unroll
        for (int a = 0; a < 5; ++a) agg[a] = make_float4(0.f, 0.f, 0.f, 0.f);
        {
            const int t = tid & 31;
            float we1col[NG];
#pragma unroll
            for (int m = 0; m < NG; ++m) we1col[m] = We1[((size_t)l * NG + m) * NG + t];
            const float be1t = be1[l * NG + t];
            const int fr = lane & 15, fg = lane >> 4, g8 = (lane >> 4) << 3;
            const float be2a = be2[l * D + (wv * 2 + 0) * 16 + fr];
            const float be2b = be2[l * D + (wv * 2 + 1) * 16 + fr];
            const __hip_bfloat16* __restrict__ WT2l = WT2 + (size_t)l * NG * D;
            const bshort8 bfrag0 = *(const bshort8*)&WT2l[((wv * 2 + 0) * 16 + fr) * 32 + g8];
            const bshort8 bfrag1 = *(const bshort8*)&WT2l[((wv * 2 + 1) * 16 + fr) * 32 + g8];

            for (int base = 0; base < cnt; base += EB) {
                const int nb = min(EB, cnt - base);
                // X1: endpoints + zero counters + e_g
                if (tid < nb) {
                    unsigned pe = eptr[base + tid];
                    sE0[tid] = (pe >> 6) & 63;
                    sE1[tid] = pe & 63;
                }
                if (tid >= 128 && tid < 128 + A_ATOMS) sCnt[tid - 128] = 0;
                {
                    int e = tid >> 3;
                    if (e < nb) {
                        float dd = sDall[base + e];
                        int m0 = (tid & 7) << 2;
                        float u0 = dd - (float)(m0 + 0);
                        float u1 = dd - (float)(m0 + 1);
                        float u2 = dd - (float)(m0 + 2);
                        float u3 = dd - (float)(m0 + 3);
                        float4 g;
                        g.x = expf(-0.5f * u0 * u0);
                        g.y = expf(-0.5f * u1 * u1);
                        g.z = expf(-0.5f * u2 * u2);
                        g.w = expf(-0.5f * u3 * u3);
                        *(float4*)&sEG[e * NG + m0] = g;
                    }
                }
                __syncthreads();
                // X2: incidence lists + h = ssp(e_g @ We1 + be1) -> bf16 [edge][k]
                if (tid < nb) {
                    int a0 = sE0[tid], a1 = sE1[tid];
                    int i0 = atomicAdd(&sCnt[a0], 1);
                    if (i0 < LCAP) sList[a0 * LCAP + i0] = (a1 << 8) | tid;
                    int i1 = atomicAdd(&sCnt[a1], 1);
                    if (i1 < LCAP) sList[a1 * LCAP + i1] = (a0 << 8) | tid;
                }
                {
                    const int e0 = tid >> 5;
#pragma unroll
                    for (int q = 0; q < 4; ++q) {
                        int e = e0 + (q << 4);
                        if (e < nb) {
                            float s = be1t;
#pragma unroll
                            for (int m = 0; m < NG; m += 4) {
                                const float4 g = *(const float4*)&sEG[e * NG + m];
                                s = fmaf(g.x, we1col[m], s);
                                s = fmaf(g.y, we1col[m + 1], s);
                                s = fmaf(g.z, we1col[m + 2], s);
                                s = fmaf(g.w, we1col[m + 3], s);
                            }
                            sHb[e * SHBP + t] = f2b(sspf(s));
                        }
                    }
                }
                __syncthreads();
                // P4: ef = h @ We2 + be2 via MFMA -> sEFs (bf16)
                {
#pragma unroll
                    for (int mt = 0; mt < 4; ++mt) {
                        union { bshort8 v; short4 s[2]; } af;
                        af.s[0] = *(const short4*)&sHb[(mt * 16 + fr) * SHBP + g8];
                        af.s[1] = *(const short4*)&sHb[(mt * 16 + fr) * SHBP + g8 + 4];
                        f32x4 c0 = (f32x4){0.f, 0.f, 0.f, 0.f};
                        f32x4 c1 = (f32x4){0.f, 0.f, 0.f, 0.f};
                        c0 = __builtin_amdgcn_mfma_f32_16x16x32_bf16(af.v, bfrag0, c0, 0, 0, 0);
                        c1 = __builtin_amdgcn_mfma_f32_16x16x32_bf16(af.v, bfrag1, c1, 0, 0, 0);
#pragma unroll
                        for (int reg = 0; reg < 4; ++reg) {
                            const int erow = mt * 16 + fg * 4 + reg;
                            if (erow < nb) {
                                sEFs[erow * 256 + (wv * 2 + 0) * 16 + fr] = f2b(c0[reg] + be2a);
                                sEFs[erow * 256 + (wv * 2 + 1) * 16 + fr] = f2b(c1[reg] + be2b);
                            }
                        }
                    }
                }
                __syncthreads();
                // P5: gather into register agg (wave drains its own 5 atoms)
#pragma unroll
                for (int a = 0; a < 5; ++a) {
                    const int row = aw + a;
                    const int n = min(sCnt[row], LCAP);
                    for (int i = 0; i < n; ++i) {
                        const int ent = sList[row * LCAP + i];
                        const int e = ent & 255, o = ent >> 8;
                        const short4 f4 = *(const short4*)&sEFs[e * 256 + c4];
                        const float4 r4 = *(const float4*)&sB[o * SRP + c4];
                        agg[a].x = fmaf(b2f(f4.x), r4.x, agg[a].x);
                        agg[a].y = fmaf(b2f(f4.y), r4.y, agg[a].y);
                        agg[a].z = fmaf(b2f(f4.z), r4.z, agg[a].z);
                        agg[a].w = fmaf(b2f(f4.w), r4.w, agg[a].w);
                    }
                }
                __syncthreads();
            }
        }
        // agg -> sB (rn dead)
#pragma unroll
        for (int a = 0; a < 5; ++a) *(float4*)&sB[(aw + a) * SRP + c4] = agg[a];
        __syncthreads();
        // ---- M2: sB = ssp(agg @ Wu1 + bu1)  (in-place: sync between acc and wb)
        {
            f32x4 acc[3][2];
            mfma_dense(sB, WT + ((size_t)(1 * 4 + l) << 16), acc, lane, wv);
            __syncthreads();
            mfma_wb<1>(acc, sB, bu1 + l * D, lane, wv);
        }
        __syncthreads();
        // ---- M3: sR += t @ Wu2 + bu2
        {
            f32x4 acc[3][2];
            mfma_dense(sB, WT + ((size_t)(2 * 4 + l) << 16), acc, lane, wv);
            mfma_wb<2>(acc, sR, bu2 + l * D, lane, wv);
        }
    }
    __syncthreads();
    if (tid < D) {
        float s = 0.f;
#pragma unroll
        for (int a = 0; a < A_ATOMS; ++a) s += sR[a * SRP + tid];
        conf_fp[conf * D + tid] = s;
    }
}

// ---------------- per-conformer molecular MLP + Boltzmann-weighted reduce ----------------
__global__ __launch_bounds__(512) void k_mol(
    const float* __restrict__ conf_fp,
    const float* __restrict__ Wm1, const float* __restrict__ bm1,
    const float* __restrict__ Wm2, const float* __restrict__ bm2,
    const float* __restrict__ boltz, float* __restrict__ mol_fp)
{
    __shared__ float cf[D];
    __shared__ float t[H_MOL];
    const int conf = blockIdx.x;
    const int tid = threadIdx.x;
    if (tid < D) cf[tid] = conf_fp[conf * D + tid];
    __syncthreads();
    if (tid < H_MOL) {
        float s = bm1[tid];
        for (int k = 0; k < D; k += 4) {
            const float4 v = *(const float4*)&cf[k];
            s = fmaf(v.x, Wm1[(k + 0) * H_MOL + tid], s);
            s = fmaf(v.y, Wm1[(k + 1) * H_MOL + tid], s);
            s = fmaf(v.z, Wm1[(k + 2) * H_MOL + tid], s);
            s = fmaf(v.w, Wm1[(k + 3) * H_MOL + tid], s);
        }
        t[tid] = sspf(s);
    }
    __syncthreads();
    {
        const int m = tid;
        float s = bm2[m];
        for (int h = 0; h < H_MOL; h += 4) {
            const float4 v = *(const float4*)&t[h];
            s = fmaf(v.x, Wm2[(h + 0) * MOLB + m], s);
            s = fmaf(v.y, Wm2[(h + 1) * MOLB + m], s);
            s = fmaf(v.z, Wm2[(h + 2) * MOLB + m], s);
            s = fmaf(v.w, Wm2[(h + 3) * MOLB + m], s);
        }
        atomicAdd(&mol_fp[(conf / N_CONFS_PER) * MOLB + m], s * boltz[conf]);
    }
}

// ---------------- final readout MLP + sigmoid ----------------
__global__ __launch_bounds__(256) void k_final(
    const float* __restrict__ mol_fp,
    const float* __restrict__ Wr1, const float* __restrict__ br1,
    const float* __restrict__ Wr2, const float* __restrict__ br2,
    float* __restrict__ out)
{
    __shared__ float mf[MOLB];
    __shared__ float t2[D];
    __shared__ float red[4];
    const int mol = blockIdx.x, tid = threadIdx.x;
    mf[tid]       = mol_fp[mol * MOLB + tid];
    mf[tid + 256] = mol_fp[mol * MOLB + tid + 256];
    __syncthreads();
    {
        float s = br1[tid];
        for (int k = 0; k < MOLB; k += 4) {
            const float4 v = *(const float4*)&mf[k];
            s = fmaf(v.x, Wr1[(k + 0) * D + tid], s);
            s = fmaf(v.y, Wr1[(k + 1) * D + tid], s);
            s = fmaf(v.z, Wr1[(k + 2) * D + tid], s);
            s = fmaf(v.w, Wr1[(k + 3) * D + tid], s);
        }
        t2[tid] = sspf(s);
    }
    __syncthreads();
    float p = t2[tid] * Wr2[tid];
#pragma unroll
    for (int o = 32; o > 0; o >>= 1) p += __shfl_down(p, o);
    if ((tid & 63) == 0) red[tid >> 6] = p;
    __syncthreads();
    if (tid == 0) {
        float logit = red[0] + red[1] + red[2] + red[3] + br2[0];
        out[mol] = 1.f / (1.f + expf(-logit));
    }
}

extern "C" void kernel_launch(void* const* d_in, const int* in_sizes, int n_in,
                              void* d_out, int out_size, void* d_ws, size_t ws_size,
                              hipStream_t stream)
{
    const int*   z     = (const int*)d_in[0];
    const float* xyz   = (const float*)d_in[1];
    const int*   nbr   = (const int*)d_in[2];
    const float* boltz = (const float*)d_in[3];
    const float* emb   = (const float*)d_in[4];
    const float* We1   = (const float*)d_in[5];
    const float* be1   = (const float*)d_in[6];
    const float* We2   = (const float*)d_in[7];
    const float* be2   = (const float*)d_in[8];
    const float* Wn    = (const float*)d_in[9];
    const float* bn    = (const float*)d_in[10];
    const float* Wu1   = (const float*)d_in[11];
    const float* bu1   = (const float*)d_in[12];
    const float* Wu2   = (const float*)d_in[13];
    const float* bu2   = (const float*)d_in[14];
    const float* Wm1   = (const float*)d_in[15];
    const float* bm1   = (const float*)d_in[16];
    const float* Wm2   = (const float*)d_in[17];
    const float* bm2   = (const float*)d_in[18];
    const float* Wr1   = (const float*)d_in[19];
    const float* br1   = (const float*)d_in[20];
    const float* Wr2   = (const float*)d_in[21];
    const float* br2   = (const float*)d_in[22];

    char* ws = (char*)d_ws;
    unsigned* cursors        = (unsigned*)ws;                   // 2560 B
    float*    mol_fp         = (float*)(ws + 2560);             // 131072 B -> 133632
    unsigned* esort          = (unsigned*)(ws + 133632);        // 2621440 B -> 2755072
    float*    conf_fp        = (float*)(ws + 2755072);          // 655360 B -> 3410432
    __hip_bfloat16* WT       = (__hip_bfloat16*)(ws + 3410432); // 1572864 B -> 4983296
    __hip_bfloat16* WT2      = (__hip_bfloat16*)(ws + 4983296); // 4*256*32*2 = 65536 B

    hipMemsetAsync(cursors, 0, 2560 + 131072, stream);          // cursors + mol_fp
    k_prep<<<3072, 256, 0, stream>>>(Wn, Wu1, Wu2, WT);
    k_prep2<<<128, 256, 0, stream>>>(We2, WT2);
    k_scatter<<<(N_EDGES + 255) / 256, 256, 0, stream>>>(nbr, cursors, esort);
    k_main<<<N_CONFS, 512, 0, stream>>>(z, xyz, emb, We1, be1, be2, bn,
                                        bu1, bu2, WT, WT2, cursors, esort, conf_fp);
    k_mol<<<N_CONFS, 512, 0, stream>>>(conf_fp, Wm1, bm1, Wm2, bm2, boltz, mol_fp);
    k_final<<<N_MOLS, 256, 0, stream>>>(mol_fp, Wr1, br1, Wr2, br2, (float*)d_out);
}